// Round 2
// baseline (3897.825 us; speedup 1.0000x reference)
//
#include <hip/hip_runtime.h>
#include <hip/hip_bf16.h>
#include <math.h>

#define B_   128
#define T_   2048
#define DIN  64
#define H_   128
#define WH_  256
#define WY_  256
#define DOUT 64

// Dual-dtype load: device inputs are either fp32 or bf16 (resolved at runtime).
__device__ __forceinline__ float ldv(const void* p, long i, bool f32) {
    return f32 ? ((const float*)p)[i]
               : __bfloat162float(((const __hip_bfloat16*)p)[i]);
}

// Dtype sniff: inspect low 16-bit halves of the first 64 uint32s of x.
// bf16-packed -> low half is a bf16 of N(0,1): exponent in [64,191] always.
// fp32        -> low half is mantissa bits: exponent field uniform (P~0.5).
#define SNIFF_DTYPE(xv, tid, sflag, f32out)                                   \
    if ((tid) == 0) sflag = 0;                                                \
    __syncthreads();                                                          \
    if ((tid) < 64) {                                                         \
        const unsigned uu = ((const unsigned*)(xv))[(tid)];                   \
        const int ee = (uu >> 7) & 0xFF;                                      \
        const unsigned long long mm = __ballot(ee >= 64 && ee <= 191);        \
        if ((tid) == 0) sflag = (__popcll(mm) >= 56) ? 0 : 1;                 \
    }                                                                         \
    __syncthreads();                                                          \
    const bool f32out = (sflag != 0);

// ---------------- Phase 1: sequential recurrence, fp32 throughout ----------
// 128 WGs (one per batch row) x 512 threads.
__global__ __launch_bounds__(512, 2) void rnn_phase1(
    const void* __restrict__ xv,
    const void* __restrict__ hW1v, const void* __restrict__ hb1v,
    const void* __restrict__ hW2v, const void* __restrict__ hb2v,
    float* __restrict__ HallF, __hip_bfloat16* __restrict__ HallB,
    const int mode,            // 0 = fp32 Hall, 1 = bf16 Hall (small ws fallback)
    void* __restrict__ outv)   // for h_final tail
{
    const int b   = blockIdx.x;
    const int tid = threadIdx.x;

    __shared__ int   sflag;
    __shared__ float hx[192];          // [0..127]=h fp32, [128..191]=x_t
    __shared__ float part1[2][256];
    __shared__ float sl[256];
    __shared__ float part2[4][128];

    SNIFF_DTYPE(xv, tid, sflag, f32);

    const int f1 = tid & 255, kh = tid >> 8;   // GEMV1: out f1, K-half kh
    const int f2 = tid & 127, kq = tid >> 7;   // GEMV2: out f2, K-quarter kq

    float W1f[96];
#pragma unroll
    for (int j = 0; j < 96; ++j) W1f[j] = ldv(hW1v, f1 * 192 + kh * 96 + j, f32);
    float W2f[64];
#pragma unroll
    for (int j = 0; j < 64; ++j) W2f[j] = ldv(hW2v, f2 * 256 + kq * 64 + j, f32);

    const float b1 = (tid < 256) ? ldv(hb1v, tid, f32) : 0.f;
    const float b2 = (tid < 128) ? ldv(hb2v, tid, f32) : 0.f;

    if (tid < 128) hx[tid] = 0.f;
    float xreg = 0.f;
    if (tid >= 448) {
        const int lane = tid - 448;
        const long xb = (long)b * (T_ * DIN);
        hx[128 + lane] = ldv(xv, xb + lane, f32);        // x_0
        xreg           = ldv(xv, xb + DIN + lane, f32);  // x_1
    }
    __syncthreads();

    for (int t = 0; t < T_; ++t) {
        // GEMV1 partial (96 MACs, hx broadcast reads, weights in regs)
        {
            const int kb = kh * 96;
            float a0 = 0.f, a1 = 0.f, a2 = 0.f, a3 = 0.f;
#pragma unroll
            for (int j = 0; j < 96; j += 4) {
                const float4 h4 = *(const float4*)&hx[kb + j];
                a0 += h4.x * W1f[j + 0];
                a1 += h4.y * W1f[j + 1];
                a2 += h4.z * W1f[j + 2];
                a3 += h4.w * W1f[j + 3];
            }
            part1[kh][f1] = (a0 + a1) + (a2 + a3);
        }
        __syncthreads();

        if (tid < 256) {
            const float v = part1[0][tid] + part1[1][tid] + b1;
            sl[tid] = v / (1.f + expf(-v));             // precise silu
        }
        if (tid >= 448) {
            const int lane = tid - 448;
            if (t + 1 < T_) hx[128 + lane] = xreg;      // install x_{t+1}
            const int tn = (t + 2 < T_) ? (t + 2) : (T_ - 1);
            xreg = ldv(xv, (long)b * (T_ * DIN) + (long)tn * DIN + lane, f32);
        }
        __syncthreads();

        // GEMV2 partial (64 MACs)
        {
            const int kb = kq * 64;
            float a0 = 0.f, a1 = 0.f, a2 = 0.f, a3 = 0.f;
#pragma unroll
            for (int j = 0; j < 64; j += 4) {
                const float4 s4 = *(const float4*)&sl[kb + j];
                a0 += s4.x * W2f[j + 0];
                a1 += s4.y * W2f[j + 1];
                a2 += s4.z * W2f[j + 2];
                a3 += s4.w * W2f[j + 3];
            }
            part2[kq][f2] = (a0 + a1) + (a2 + a3);
        }
        __syncthreads();

        if (tid < 128) {
            const float hn = part2[0][tid] + part2[1][tid] + part2[2][tid]
                           + part2[3][tid] + b2;
            hx[tid] = hn;
            const long idx = ((long)t * B_ + b) * H_ + tid;
            if (mode == 0) HallF[idx] = hn;
            else           HallB[idx] = __float2bfloat16(hn);
        }
        __syncthreads();
    }

    if (tid < 128) {
        const long o = (long)B_ * T_ * DOUT + (long)b * H_ + tid;
        if (f32) ((float*)outv)[o] = hx[tid];
        else     ((__hip_bfloat16*)outv)[o] = __float2bfloat16(hx[tid]);
    }
}

// ---------------- Phase 2: y-MLP over all (t,b), fp32 VALU -----------------
// 2048 WGs (one per t) x 512 threads. yW1 row-halves + yW2 shares in regs.
__global__ __launch_bounds__(512, 2) void rnn_phase2(
    const float* __restrict__ HallF, const __hip_bfloat16* __restrict__ HallB,
    const int mode,
    const void* __restrict__ yW1v, const void* __restrict__ yb1v,
    const void* __restrict__ yW2v, const void* __restrict__ yb2v,
    const void* __restrict__ xv,   // sniff only
    void* __restrict__ outv)
{
    const int t   = blockIdx.x;
    const int tid = threadIdx.x;

    __shared__ int   sflag;
    __shared__ float hblk[B_][H_];     // 64 KB
    __shared__ float part[2][256];
    __shared__ float u[256];
    __shared__ float party[8][64];

    SNIFF_DTYPE(xv, tid, sflag, f32);

    const int f = tid & 255, half = tid >> 8;   // Y1: out f, K-half
    const int o = tid & 63,  q    = tid >> 6;   // Y2: out o, K-eighth

    float Y1r[64];
#pragma unroll
    for (int j = 0; j < 64; ++j) Y1r[j] = ldv(yW1v, f * 128 + half * 64 + j, f32);
    float Y2r[32];
#pragma unroll
    for (int j = 0; j < 32; ++j) Y2r[j] = ldv(yW2v, o * 256 + q * 32 + j, f32);
    const float b1 = (tid < 256) ? ldv(yb1v, tid, f32) : 0.f;
    const float b2 = (tid < 64)  ? ldv(yb2v, tid, f32) : 0.f;

    // Load this t's h rows (contiguous in Hall: [(t*B)*H, (t*B+B)*H))
    {
        const long base = (long)t * (B_ * H_);
        if (mode == 0) {
            const float4* src = (const float4*)(HallF + base);
            float4* dst = (float4*)hblk;
            for (int i = tid; i < (B_ * H_) / 4; i += 512) dst[i] = src[i];
        } else {
            float* dst = (float*)hblk;
            for (int i = tid; i < B_ * H_; i += 512)
                dst[i] = __bfloat162float(HallB[base + i]);
        }
    }
    __syncthreads();

    for (int b = 0; b < B_; ++b) {
        // Y1 partial: u_pre[f] over K-half
        float acc = 0.f;
        {
            const float* hr = &hblk[b][half * 64];
#pragma unroll
            for (int j = 0; j < 64; j += 4) {
                const float4 h4 = *(const float4*)&hr[j];
                acc += h4.x * Y1r[j + 0] + h4.y * Y1r[j + 1]
                     + h4.z * Y1r[j + 2] + h4.w * Y1r[j + 3];
            }
        }
        part[half][f] = acc;
        __syncthreads();

        if (tid < 256) {
            const float v = part[0][tid] + part[1][tid] + b1;
            u[tid] = v / (1.f + expf(-v));
        }
        __syncthreads();

        // Y2 partial
        float a2 = 0.f;
        {
            const float* ur = &u[q * 32];
#pragma unroll
            for (int j = 0; j < 32; j += 4) {
                const float4 u4 = *(const float4*)&ur[j];
                a2 += u4.x * Y2r[j + 0] + u4.y * Y2r[j + 1]
                    + u4.z * Y2r[j + 2] + u4.w * Y2r[j + 3];
            }
        }
        party[q][o] = a2;
        __syncthreads();

        if (tid < 64) {
            float y = b2;
#pragma unroll
            for (int qq = 0; qq < 8; ++qq) y += party[qq][tid];
            const long oi = (long)b * (T_ * DOUT) + (long)t * DOUT + tid;
            if (f32) ((float*)outv)[oi] = y;
            else     ((__hip_bfloat16*)outv)[oi] = __float2bfloat16(y);
        }
        // no 4th barrier needed: next writes to part/u/party are each
        // separated from this row's reads by >=1 barrier.
    }
}

extern "C" void kernel_launch(void* const* d_in, const int* in_sizes, int n_in,
                              void* d_out, int out_size, void* d_ws, size_t ws_size,
                              hipStream_t stream) {
    const void* xv   = d_in[0];
    const void* hW1v = d_in[1];
    const void* hb1v = d_in[2];
    const void* hW2v = d_in[3];
    const void* hb2v = d_in[4];
    const void* yW1v = d_in[5];
    const void* yb1v = d_in[6];
    const void* yW2v = d_in[7];
    const void* yb2v = d_in[8];

    const size_t needF = (size_t)T_ * B_ * H_ * sizeof(float);   // 134 MB
    const int mode = (ws_size >= needF) ? 0 : 1;                 // fp32 vs bf16 Hall

    float* HallF = (float*)d_ws;
    __hip_bfloat16* HallB = (__hip_bfloat16*)d_ws;

    rnn_phase1<<<128, 512, 0, stream>>>(xv, hW1v, hb1v, hW2v, hb2v,
                                        HallF, HallB, mode, d_out);
    rnn_phase2<<<2048, 512, 0, stream>>>(HallF, HallB, mode,
                                         yW1v, yb1v, yW2v, yb2v, xv, d_out);
}

// Round 3
// 3146.766 us; speedup vs baseline: 1.2387x; 1.2387x over previous
//
#include <hip/hip_runtime.h>
#include <hip/hip_bf16.h>
#include <math.h>

#define B_   128
#define T_   2048
#define DIN  64
#define H_   128
#define WH_  256
#define WY_  256
#define DOUT 64

typedef __attribute__((ext_vector_type(8))) short short8;
typedef __attribute__((ext_vector_type(4))) float floatx4;

// Raw barrier: wait LDS ops only (no vmcnt drain -> global stores fly free).
__device__ __forceinline__ void bar_lds() {
    asm volatile("s_waitcnt lgkmcnt(0)\n\ts_barrier" ::: "memory");
}

__device__ __forceinline__ short bf16_hi(float f) {
    __hip_bfloat16 h = __float2bfloat16(f);
    return *reinterpret_cast<short*>(&h);
}
__device__ __forceinline__ float bf16_val(short s) {
    __hip_bfloat16 h = *reinterpret_cast<__hip_bfloat16*>(&s);
    return __bfloat162float(h);
}
// split fp32 -> hi + lo bf16 (lo = round(f - hi))
__device__ __forceinline__ void split8(const float* v, short8& hi, short8& lo) {
#pragma unroll
    for (int j = 0; j < 8; ++j) {
        const float f = v[j];
        const short h = bf16_hi(f);
        hi[j] = h;
        lo[j] = bf16_hi(f - bf16_val(h));
    }
}

// ---------------- Phase 1: sequential recurrence, fp32 VALU ----------------
// 128 WGs x 512 threads. F-tile 4 GEMVs; raw barriers; fire-and-forget Hall.
__global__ __launch_bounds__(512, 2) void rnn_phase1(
    const float* __restrict__ x,
    const float* __restrict__ hW1, const float* __restrict__ hb1,
    const float* __restrict__ hW2, const float* __restrict__ hb2,
    float* __restrict__ Hall,      // [T_*B_, H_] fp32
    float* __restrict__ outF)      // d_out fp32; hfinal at tail
{
    const int b   = blockIdx.x;
    const int tid = threadIdx.x;

    __shared__ float hx[192];             // [0..127]=h, [128..191]=x_t
    __shared__ float part1[8][257];       // padded: combine reads conflict-free
    __shared__ float sl[256];
    __shared__ float part2[16][129];

    // GEMV1: outputs f*64+fg1 (f=0..3), K-chunk ks1*24..+24
    const int fg1 = tid & 63, ks1 = tid >> 6;
    // GEMV2: outputs f*32+fg2 (f=0..3), K-chunk ks2*16..+16
    const int fg2 = tid & 31, ks2 = tid >> 5;

    float W1r[4][24];
#pragma unroll
    for (int f = 0; f < 4; ++f)
#pragma unroll
        for (int j = 0; j < 24; ++j)
            W1r[f][j] = hW1[(f * 64 + fg1) * 192 + ks1 * 24 + j];
    float W2r[4][16];
#pragma unroll
    for (int f = 0; f < 4; ++f)
#pragma unroll
        for (int j = 0; j < 16; ++j)
            W2r[f][j] = hW2[(f * 32 + fg2) * 256 + ks2 * 16 + j];

    const float b1 = (tid < 256) ? hb1[tid] : 0.f;
    const float b2 = (tid < 128) ? hb2[tid] : 0.f;

    if (tid < 128) hx[tid] = 0.f;
    float xreg = 0.f;
    if (tid >= 448) {
        const int lane = tid - 448;
        const long xb = (long)b * (T_ * DIN);
        hx[128 + lane] = x[xb + lane];        // x_0
        xreg           = x[xb + DIN + lane];  // x_1
    }
    __syncthreads();

    for (int t = 0; t < T_; ++t) {
        // ---- A: GEMV1 partials (broadcast hx reads feed 4 outputs each)
        {
            float a0 = 0.f, a1 = 0.f, a2 = 0.f, a3 = 0.f;
            const float* hp = &hx[ks1 * 24];
#pragma unroll
            for (int j = 0; j < 24; j += 4) {
                const float4 h4 = *(const float4*)&hp[j];
                a0 += h4.x * W1r[0][j] + h4.y * W1r[0][j+1] + h4.z * W1r[0][j+2] + h4.w * W1r[0][j+3];
                a1 += h4.x * W1r[1][j] + h4.y * W1r[1][j+1] + h4.z * W1r[1][j+2] + h4.w * W1r[1][j+3];
                a2 += h4.x * W1r[2][j] + h4.y * W1r[2][j+1] + h4.z * W1r[2][j+2] + h4.w * W1r[2][j+3];
                a3 += h4.x * W1r[3][j] + h4.y * W1r[3][j+1] + h4.z * W1r[3][j+2] + h4.w * W1r[3][j+3];
            }
            part1[ks1][0 * 64 + fg1] = a0;    // lane-stride-1 writes: conflict-free
            part1[ks1][1 * 64 + fg1] = a1;
            part1[ks1][2 * 64 + fg1] = a2;
            part1[ks1][3 * 64 + fg1] = a3;
        }
        bar_lds();

        // ---- B: combine + silu (precise expf, matches round-2 numerics)
        if (tid < 256) {
            float v = b1;
#pragma unroll
            for (int k = 0; k < 8; ++k) v += part1[k][tid];
            sl[tid] = v / (1.f + expf(-v));
        }
        if (tid >= 448) {
            const int lane = tid - 448;
            if (t + 1 < T_) hx[128 + lane] = xreg;
            const int tn = (t + 2 < T_) ? (t + 2) : (T_ - 1);
            xreg = x[(long)b * (T_ * DIN) + (long)tn * DIN + lane];
        }
        bar_lds();

        // ---- C: GEMV2 partials
        {
            float c0 = 0.f, c1 = 0.f, c2 = 0.f, c3 = 0.f;
            const float* sp = &sl[ks2 * 16];
#pragma unroll
            for (int j = 0; j < 16; j += 4) {
                const float4 s4 = *(const float4*)&sp[j];
                c0 += s4.x * W2r[0][j] + s4.y * W2r[0][j+1] + s4.z * W2r[0][j+2] + s4.w * W2r[0][j+3];
                c1 += s4.x * W2r[1][j] + s4.y * W2r[1][j+1] + s4.z * W2r[1][j+2] + s4.w * W2r[1][j+3];
                c2 += s4.x * W2r[2][j] + s4.y * W2r[2][j+1] + s4.z * W2r[2][j+2] + s4.w * W2r[2][j+3];
                c3 += s4.x * W2r[3][j] + s4.y * W2r[3][j+1] + s4.z * W2r[3][j+2] + s4.w * W2r[3][j+3];
            }
            part2[ks2][0 * 32 + fg2] = c0;
            part2[ks2][1 * 32 + fg2] = c1;
            part2[ks2][2 * 32 + fg2] = c2;
            part2[ks2][3 * 32 + fg2] = c3;
        }
        bar_lds();

        // ---- D: combine -> h_new; LDS + fire-and-forget global store
        if (tid < 128) {
            float hn = b2;
#pragma unroll
            for (int k = 0; k < 16; ++k) hn += part2[k][tid];
            hx[tid] = hn;
            Hall[((long)t * B_ + b) * H_ + tid] = hn;   // no barrier drain (raw bars)
        }
        bar_lds();
    }

    if (tid < 128)
        outF[(long)B_ * T_ * DOUT + (long)b * H_ + tid] = hx[tid];
}

// -------- pre-split y-weights into MFMA-frag-linear bf16 hi/lo layout ------
// Y1f: [nt(16)][ks(4)][lane(64)][j(8)] hi, then +32768 lo  (shorts)
// Y2f: [nt2(4)][ks(8)][lane(64)][j(8)] hi, then +16384 lo
__global__ __launch_bounds__(256) void presplit(
    const float* __restrict__ yW1, const float* __restrict__ yW2,
    short* __restrict__ Y1f, short* __restrict__ Y2f)
{
    const int i = blockIdx.x * 256 + threadIdx.x;
    if (i < 32768) {
        const int j = i & 7, lane = (i >> 3) & 63, ks = (i >> 9) & 3, nt = i >> 11;
        const float v = yW1[(nt * 16 + (lane & 15)) * 128 + (lane >> 4) * 8 + ks * 32 + j];
        const short h = bf16_hi(v);
        Y1f[i]         = h;
        Y1f[32768 + i] = bf16_hi(v - bf16_val(h));
    }
    if (i < 16384) {
        const int j = i & 7, lane = (i >> 3) & 63, ks = (i >> 9) & 7, nt2 = i >> 12;
        const float v = yW2[(nt2 * 16 + (lane & 15)) * 256 + (lane >> 4) * 8 + ks * 32 + j];
        const short h = bf16_hi(v);
        Y2f[i]         = h;
        Y2f[16384 + i] = bf16_hi(v - bf16_val(h));
    }
}

// ---------------- Phase 2: y-MLP via MFMA, bf16 hi/lo split ----------------
// 1024 WGs x 256 thr (4 waves). Wave owns a 16-row tile; 4 tiles per wave.
__global__ __launch_bounds__(256, 2) void rnn_phase2(
    const float* __restrict__ Hall,
    const float* __restrict__ yW1, const float* __restrict__ yb1,
    const float* __restrict__ yW2, const float* __restrict__ yb2,
    const short* __restrict__ Y1f, const short* __restrict__ Y2f,
    const int onfly,
    float* __restrict__ out)
{
    __shared__ short u_hi[4][16 * 256];   // per-wave 8KB
    __shared__ short u_lo[4][16 * 256];   // per-wave 8KB

    const int tid  = threadIdx.x;
    const int wave = tid >> 6;
    const int lane = tid & 63;
    const int l15  = lane & 15;
    const int lg   = lane >> 4;

    char* uh = reinterpret_cast<char*>(u_hi[wave]);
    char* ul = reinterpret_cast<char*>(u_lo[wave]);
    const int wglobal = blockIdx.x * 4 + wave;        // 0..4095

    const floatx4 zero4 = {0.f, 0.f, 0.f, 0.f};

    for (int it = 0; it < 4; ++it) {
        const long tile = (long)wglobal + 4096L * it; // 0..16383
        const long r0   = tile * 16;

        // ---- A-frags from Hall (fp32 -> hi/lo bf16)
        short8 aHhi[4], aHlo[4];
#pragma unroll
        for (int ks = 0; ks < 4; ++ks) {
            float av[8];
            const float* p = Hall + (r0 + l15) * 128 + lg * 8 + ks * 32;
            *(float4*)&av[0] = *(const float4*)&p[0];
            *(float4*)&av[4] = *(const float4*)&p[4];
            split8(av, aHhi[ks], aHlo[ks]);
        }

        // ---- GEMM1 + silu -> u (hi/lo) in LDS, XOR-swizzled
#pragma unroll
        for (int nt = 0; nt < 16; ++nt) {
            floatx4 acc = zero4;
#pragma unroll
            for (int ks = 0; ks < 4; ++ks) {
                short8 bhi, blo;
                if (onfly) {
                    float bv[8];
                    const float* p = yW1 + (nt * 16 + l15) * 128 + lg * 8 + ks * 32;
                    *(float4*)&bv[0] = *(const float4*)&p[0];
                    *(float4*)&bv[4] = *(const float4*)&p[4];
                    split8(bv, bhi, blo);
                } else {
                    bhi = *(const short8*)(Y1f + ((nt * 4 + ks) * 512 + lane * 8));
                    blo = *(const short8*)(Y1f + 32768 + ((nt * 4 + ks) * 512 + lane * 8));
                }
                acc = __builtin_amdgcn_mfma_f32_16x16x32_bf16(aHhi[ks], bhi, acc, 0, 0, 0);
                acc = __builtin_amdgcn_mfma_f32_16x16x32_bf16(aHlo[ks], bhi, acc, 0, 0, 0);
                acc = __builtin_amdgcn_mfma_f32_16x16x32_bf16(aHhi[ks], blo, acc, 0, 0, 0);
            }
            const int col  = nt * 16 + l15;
            const float bias = yb1[col];
#pragma unroll
            for (int r = 0; r < 4; ++r) {
                const int row = lg * 4 + r;
                const float v = acc[r] + bias;
                const float s = v / (1.f + __expf(-v));
                int byte = row * 512 + col * 2;
                byte ^= ((row & 7) << 4);
                const short h = bf16_hi(s);
                *reinterpret_cast<short*>(uh + byte) = h;
                *reinterpret_cast<short*>(ul + byte) = bf16_hi(s - bf16_val(h));
            }
        }
        asm volatile("s_waitcnt lgkmcnt(0)" ::: "memory");

        // ---- GEMM2: y = u @ yW2^T
        floatx4 acc2[4] = {zero4, zero4, zero4, zero4};
#pragma unroll
        for (int ks = 0; ks < 8; ++ks) {
            int byte = l15 * 512 + (lg * 8 + ks * 32) * 2;
            byte ^= ((l15 & 7) << 4);
            const short8 ahi = *(const short8*)(uh + byte);
            const short8 alo = *(const short8*)(ul + byte);
#pragma unroll
            for (int nt = 0; nt < 4; ++nt) {
                short8 bhi, blo;
                if (onfly) {
                    float bv[8];
                    const float* p = yW2 + (nt * 16 + l15) * 256 + lg * 8 + ks * 32;
                    *(float4*)&bv[0] = *(const float4*)&p[0];
                    *(float4*)&bv[4] = *(const float4*)&p[4];
                    split8(bv, bhi, blo);
                } else {
                    bhi = *(const short8*)(Y2f + ((nt * 8 + ks) * 512 + lane * 8));
                    blo = *(const short8*)(Y2f + 16384 + ((nt * 8 + ks) * 512 + lane * 8));
                }
                acc2[nt] = __builtin_amdgcn_mfma_f32_16x16x32_bf16(ahi, bhi, acc2[nt], 0, 0, 0);
                acc2[nt] = __builtin_amdgcn_mfma_f32_16x16x32_bf16(alo, bhi, acc2[nt], 0, 0, 0);
                acc2[nt] = __builtin_amdgcn_mfma_f32_16x16x32_bf16(ahi, blo, acc2[nt], 0, 0, 0);
            }
        }

        // ---- epilogue: bias + fp32 store (D: col=l15+16nt, row=lg*4+r)
#pragma unroll
        for (int nt = 0; nt < 4; ++nt) {
            const int col  = nt * 16 + l15;
            const float bias = yb2[col];
#pragma unroll
            for (int r = 0; r < 4; ++r) {
                const long R  = r0 + lg * 4 + r;     // = t*B_ + b
                const long bb = R & (B_ - 1);
                const long tt = R >> 7;
                out[bb * (T_ * DOUT) + tt * DOUT + col] = acc2[nt][r] + bias;
            }
        }
    }
}

extern "C" void kernel_launch(void* const* d_in, const int* in_sizes, int n_in,
                              void* d_out, int out_size, void* d_ws, size_t ws_size,
                              hipStream_t stream) {
    const float* x   = (const float*)d_in[0];
    const float* hW1 = (const float*)d_in[1];
    const float* hb1 = (const float*)d_in[2];
    const float* hW2 = (const float*)d_in[3];
    const float* hb2 = (const float*)d_in[4];
    const float* yW1 = (const float*)d_in[5];
    const float* yb1 = (const float*)d_in[6];
    const float* yW2 = (const float*)d_in[7];
    const float* yb2 = (const float*)d_in[8];

    float* out  = (float*)d_out;
    float* Hall = (float*)d_ws;
    const size_t hallBytes = (size_t)T_ * B_ * H_ * sizeof(float);   // 134.2 MB
    const size_t fragBytes = (size_t)(65536 + 32768) * sizeof(short); // 192 KB

    const int onfly = (ws_size < hallBytes + fragBytes) ? 1 : 0;
    short* Y1f = (short*)((char*)d_ws + hallBytes);
    short* Y2f = Y1f + 65536;

    rnn_phase1<<<128, 512, 0, stream>>>(x, hW1, hb1, hW2, hb2, Hall, out);
    if (!onfly)
        presplit<<<128, 256, 0, stream>>>(yW1, yW2, Y1f, Y2f);
    rnn_phase2<<<1024, 256, 0, stream>>>(Hall, yW1, yb1, yW2, yb2,
                                         Y1f, Y2f, onfly, out);
}